// Round 1
// baseline (47.519 us; speedup 1.0000x reference)
//
#include <hip/hip_runtime.h>

// ARLoss: loss = mean(max(0, |input - round(target)| - |input - z| + (pos ? 1e-6 : 0)))
//   where pos = (input - round(target)) >= 0, z = pos ? ceil(input) : floor(input)
// Memory-bound streaming reduction over 2 x 8192 x 4096 fp32 inputs (268 MB).

#define EPSF 1e-6f

constexpr int THREADS = 256;
constexpr int MAX_BLOCKS = 2048;

__global__ __launch_bounds__(THREADS) void arloss_partial_kernel(
    const float4* __restrict__ x4, const float4* __restrict__ t4,
    double* __restrict__ partial, int n4) {
    double sum = 0.0;
    const int stride = gridDim.x * blockDim.x;
    for (int i = blockIdx.x * blockDim.x + threadIdx.x; i < n4; i += stride) {
        const float4 xv = x4[i];
        const float4 tv = t4[i];
        const float xs[4] = {xv.x, xv.y, xv.z, xv.w};
        const float ts[4] = {tv.x, tv.y, tv.z, tv.w};
#pragma unroll
        for (int j = 0; j < 4; ++j) {
            const float x = xs[j];
            const float c = rintf(ts[j]);          // round-half-to-even == jnp.round
            const float d = x - c;
            const bool pos = (d >= 0.0f);
            const float z = pos ? ceilf(x) : floorf(x);
            const float margin = fabsf(d) - fabsf(x - z) + (pos ? EPSF : 0.0f);
            sum += (double)fmaxf(0.0f, margin);
        }
    }
    // wave (64-lane) reduction
#pragma unroll
    for (int off = 32; off > 0; off >>= 1)
        sum += __shfl_down(sum, off, 64);
    __shared__ double lds[THREADS / 64];
    const int lane = threadIdx.x & 63;
    const int wid  = threadIdx.x >> 6;
    if (lane == 0) lds[wid] = sum;
    __syncthreads();
    if (threadIdx.x == 0) {
        double s = 0.0;
#pragma unroll
        for (int w = 0; w < THREADS / 64; ++w) s += lds[w];
        partial[blockIdx.x] = s;   // one deterministic write per block, no atomics
    }
}

__global__ __launch_bounds__(THREADS) void arloss_final_kernel(
    const double* __restrict__ partial, float* __restrict__ out,
    int nblocks, double inv_n) {
    double sum = 0.0;
    for (int i = threadIdx.x; i < nblocks; i += blockDim.x)
        sum += partial[i];
#pragma unroll
    for (int off = 32; off > 0; off >>= 1)
        sum += __shfl_down(sum, off, 64);
    __shared__ double lds[THREADS / 64];
    const int lane = threadIdx.x & 63;
    const int wid  = threadIdx.x >> 6;
    if (lane == 0) lds[wid] = sum;
    __syncthreads();
    if (threadIdx.x == 0) {
        double s = 0.0;
#pragma unroll
        for (int w = 0; w < THREADS / 64; ++w) s += lds[w];
        out[0] = (float)(s * inv_n);
    }
}

extern "C" void kernel_launch(void* const* d_in, const int* in_sizes, int n_in,
                              void* d_out, int out_size, void* d_ws, size_t ws_size,
                              hipStream_t stream) {
    const float* input  = (const float*)d_in[0];
    const float* target = (const float*)d_in[1];
    float* out = (float*)d_out;

    const long long n = (long long)in_sizes[0];   // 33,554,432 (divisible by 4)
    const int n4 = (int)(n / 4);

    int blocks = MAX_BLOCKS;
    const int max_ws_blocks = (int)(ws_size / sizeof(double));
    if (blocks > max_ws_blocks) blocks = max_ws_blocks > 0 ? max_ws_blocks : 1;

    double* partial = (double*)d_ws;

    arloss_partial_kernel<<<blocks, THREADS, 0, stream>>>(
        (const float4*)input, (const float4*)target, partial, n4);
    arloss_final_kernel<<<1, THREADS, 0, stream>>>(
        partial, out, blocks, 1.0 / (double)n);
}